// Round 10
// baseline (108.846 us; speedup 1.0000x reference)
//
#include <hip/hip_runtime.h>
#include <hip/hip_fp16.h>
#include <math.h>

#define VFS_EPS 1e-7f

constexpr int V_ = 8, F_ = 64, H_ = 256, W_ = 256, G_ = 128, S_ = 512;
constexpr int HW_ = H_ * W_;
constexpr int TPX = 512;  // pixels per transpose tile

__device__ __forceinline__ __half2 vfs_uint_as_half2(uint u) {
    union { uint u; __half2 h; } c;
    c.u = u;
    return c.h;
}

// -------- K0: transpose+convert [V][F][HW] f32 -> [V][HW][F] f16 --------
// Validated R4-R8: ~27 us (2KB channel runs in, 64KB contiguous out) --
// at HBM roofline for its ~134-168 MB of traffic.
__global__ __launch_bounds__(512) void vfs_transpose_h(const float* __restrict__ src,
                                                       __half* __restrict__ dst) {
    __shared__ ushort L[TPX][64];  // 64 KB
    const int v = blockIdx.y;
    const int p0 = blockIdx.x * TPX;
    const int t = threadIdx.x;
    const float* s = src + (size_t)v * F_ * HW_ + p0;
#pragma unroll 8
    for (int c = 0; c < F_; ++c) {
        const float val = s[(size_t)c * HW_ + t];
        const int os = (c >> 3) ^ (t & 7);
        L[t][os * 8 + (c & 7)] = __half_as_ushort(__float2half(val));
    }
    __syncthreads();
    __half* d = dst + ((size_t)v * HW_ + p0) * F_;
#pragma unroll
    for (int i = 0; i < 8; ++i) {
        const int j = i * 512 + t;
        const int p = j >> 3;
        const int o = j & 7;
        const int os = o ^ (p & 7);
        const uint4 val = *reinterpret_cast<const uint4*>(&L[p][os * 8]);
        *reinterpret_cast<uint4*>(&d[(size_t)j * 8]) = val;
    }
}

// -------- K1 (f16 ws): h2 gathers + fully precomputed per-(s,view) algebra ----
// Phase A stashes per (s,view): corner word-indices uint4, weight-prescaled
// bilinear factors float4 (zeroed when corner invalid), and rw = 1/w.
// Phase B inner loop is branchless straight-line: 3 LDS reads + 4 gathers +
// cvt + fma. Structure/occupancy otherwise identical to R5 (proven 50us).
__global__ __launch_bounds__(256) void vfs_sampler_h2(
    const __half* __restrict__ feat,
    const float* __restrict__ Km, const float* __restrict__ Em,
    const float* __restrict__ dst, const float* __restrict__ grids,
    const float* __restrict__ vis, const float* __restrict__ normals,
    const float* __restrict__ cc, float* __restrict__ out) {
    __shared__ uint4  wqi[64][8];  // corner word-pixel indices      (8 KB)
    __shared__ float4 wqf[64][8];  // w-prescaled bilinear factors   (8 KB)
    __shared__ float  wrw[64][8];  // 1/w                            (2 KB)
    __shared__ float stgM[64][65]; // mean staging                  (16.6 KB)
    __shared__ float stgV[64][65]; // var staging                   (16.6 KB)

    const int g = blockIdx.x >> 3;
    const int sb = (blockIdx.x & 7) * 64;
    const int t = threadIdx.x;
    const int wave = t >> 6;
    const int lane = t & 63;

    // ---- Phase A: lane = (point8, view8); full per-(s,view) precompute ----
    {
        const int vL = lane & 7;
        const int pL = lane >> 3;
        const float nx = normals[g * 3 + 0];
        const float ny = normals[g * 3 + 1];
        const float nz = normals[g * 3 + 2];
#pragma unroll
        for (int grp = 0; grp < 2; ++grp) {
            const int sl = wave * 16 + grp * 8 + pL;
            const int s = sb + sl;
            const float px = grids[(g * 3 + 0) * S_ + s];
            const float py = grids[(g * 3 + 1) * S_ + s];
            const float pz = grids[(g * 3 + 2) * S_ + s];
            const float* Ev = Em + vL * 12;
            const float pi0 = Ev[0] * px + Ev[1] * py + Ev[2] * pz + Ev[3];
            const float pi1 = Ev[4] * px + Ev[5] * py + Ev[6] * pz + Ev[7];
            float z = Ev[8] * px + Ev[9] * py + Ev[10] * pz + Ev[11];
            if (fabsf(z) < VFS_EPS) z = 1.0f;
            const float xn = pi0 / z;
            const float yn = pi1 / z;
            const float r2 = xn * xn + yn * yn;
            const float fd = 1.0f + dst[vL * 2 + 0] * r2 + dst[vL * 2 + 1] * r2 * r2;
            const float xd = xn * fd, yd = yn * fd;
            const float* Kv = Km + vL * 9;
            const float pk0 = Kv[0] * xd + Kv[1] * yd + Kv[2];
            const float pk1 = Kv[3] * xd + Kv[4] * yd + Kv[5];
            const float u = 2.0f * pk0 / (W_ - 1.0f) - 1.0f;
            const float vq = 2.0f * pk1 / (H_ - 1.0f) - 1.0f;
            const bool inside = (u >= -1.0f) && (u <= 1.0f) && (vq >= -1.0f) && (vq <= 1.0f);
            const float x = (u + 1.0f) * (W_ * 0.5f) - 0.5f;
            const float y = (vq + 1.0f) * (H_ * 0.5f) - 0.5f;
            const float x0f = floorf(x), y0f = floorf(y);
            const float wx = x - x0f, wy = y - y0f;
            const int x0 = (int)x0f, y0 = (int)y0f;
            const float dx = px - cc[vL * 3 + 0];
            const float dy = py - cc[vL * 3 + 1];
            const float dz = pz - cc[vL * 3 + 2];
            float nrm = sqrtf(dx * dx + dy * dy + dz * dz);
            nrm = fmaxf(nrm, 1e-12f);
            float cosv = (dx * nx + dy * ny + dz * nz) / nrm;
            cosv = fminf(cosv, 0.0f);
            const float wraw = vis[vL * G_ + g] * (-cosv) * (inside ? 1.0f : 0.0f);
            const float bx = 50.0f * wraw;
            float w = (bx > 5.0f) ? wraw : (log1pf(expf(bx)) * (1.0f / 50.0f));
            float wsum = w;
            wsum += __shfl_xor(wsum, 1);
            wsum += __shfl_xor(wsum, 2);
            wsum += __shfl_xor(wsum, 4);
            w = w / wsum;  // w > 0 always (softplus(0) = ln2/50)

            // --- corner precompute ---
            const bool vx0 = (x0 >= 0) & (x0 < W_);
            const bool vx1 = (x0 >= -1) & (x0 < W_ - 1);
            const bool vy0 = (y0 >= 0) & (y0 < H_);
            const bool vy1 = (y0 >= -1) & (y0 < H_ - 1);
            const int xc0 = min(max(x0, 0), W_ - 1);
            const int xc1 = min(max(x0 + 1, 0), W_ - 1);
            const int yc0 = min(max(y0, 0), H_ - 1);
            const int yc1 = min(max(y0 + 1, 0), H_ - 1);
            const uint pbase = (uint)(vL * HW_);
            wqi[sl][vL] = make_uint4(pbase + (uint)(yc0 * W_ + xc0),
                                     pbase + (uint)(yc0 * W_ + xc1),
                                     pbase + (uint)(yc1 * W_ + xc0),
                                     pbase + (uint)(yc1 * W_ + xc1));
            const float f00 = (vx0 & vy0) ? (1.f - wx) * (1.f - wy) * w : 0.f;
            const float f01 = (vx1 & vy0) ? wx * (1.f - wy) * w : 0.f;
            const float f10 = (vx0 & vy1) ? (1.f - wx) * wy * w : 0.f;
            const float f11 = (vx1 & vy1) ? wx * wy * w : 0.f;
            wqf[sl][vL] = make_float4(f00, f01, f10, f11);
            wrw[sl][vL] = 1.0f / w;
        }
    }
    __syncthreads();

    // ---- Phase B: wave = 2 points x 32 ch-pairs; branchless hot loop ----
    const int sub = lane >> 5;  // which point of the pair
    const int cp = lane & 31;   // channel pair -> channels 2cp, 2cp+1
    const uint* fp = reinterpret_cast<const uint*>(feat);
#pragma unroll 2
    for (int jj = 0; jj < 8; ++jj) {
        const int sl = wave * 16 + jj * 2 + sub;
        float mx = 0.f, my = 0.f, qx = 0.f, qy = 0.f;
#pragma unroll
        for (int v = 0; v < 8; ++v) {
            const uint4 I = wqi[sl][v];
            const float4 Fw = wqf[sl][v];
            const float rw = wrw[sl][v];
            const float2 g00 = __half22float2(vfs_uint_as_half2(fp[(I.x << 5) + (uint)cp]));
            const float2 g01 = __half22float2(vfs_uint_as_half2(fp[(I.y << 5) + (uint)cp]));
            const float2 g10 = __half22float2(vfs_uint_as_half2(fp[(I.z << 5) + (uint)cp]));
            const float2 g11 = __half22float2(vfs_uint_as_half2(fp[(I.w << 5) + (uint)cp]));
            const float wfex = g00.x * Fw.x + g01.x * Fw.y + g10.x * Fw.z + g11.x * Fw.w;
            const float wfey = g00.y * Fw.x + g01.y * Fw.y + g10.y * Fw.z + g11.y * Fw.w;
            mx += wfex;
            my += wfey;
            qx += wfex * wfex * rw;   // = w * fe^2
            qy += wfey * wfey * rw;
        }
        stgM[sl][2 * cp + 0] = mx;
        stgM[sl][2 * cp + 1] = my;
        stgV[sl][2 * cp + 0] = qx - mx * mx;
        stgV[sl][2 * cp + 1] = qy - my * my;
    }
    __syncthreads();

    // ---- coalesced write-out (R5-proven) ----
#pragma unroll
    for (int i = 0; i < 16; ++i) {
        const int e = t + i * 256;
        const int f = e >> 6;
        const int sl = e & 63;
        out[((size_t)(g * 2 * F_ + f)) * S_ + sb + sl] = stgM[sl][f];
    }
#pragma unroll
    for (int i = 0; i < 16; ++i) {
        const int e = t + i * 256;
        const int f = e >> 6;
        const int sl = e & 63;
        out[((size_t)(g * 2 * F_ + F_ + f)) * S_ + sb + sl] = stgV[sl][f];
    }
}

// -------- K1 fallback (raw f32 layout), from R2 (validated) --------
__global__ __launch_bounds__(256) void vfs_sampler_f32(
    const float* __restrict__ feat,
    const float* __restrict__ Km, const float* __restrict__ Em,
    const float* __restrict__ dst, const float* __restrict__ grids,
    const float* __restrict__ vis, const float* __restrict__ normals,
    const float* __restrict__ cc, float* __restrict__ out) {
    __shared__ float4 wp[64][8];
    __shared__ float wv[64][8];
    __shared__ float stg[64][65];

    const int g = blockIdx.x >> 3;
    const int sb = (blockIdx.x & 7) * 64;
    const int t = threadIdx.x;
    const int wave = t >> 6;
    const int lane = t & 63;
    const int vL = lane & 7;
    const int pL = lane >> 3;

    const float nx = normals[g * 3 + 0];
    const float ny = normals[g * 3 + 1];
    const float nz = normals[g * 3 + 2];

#pragma unroll
    for (int grp = 0; grp < 2; ++grp) {
        const int sl = wave * 16 + grp * 8 + pL;
        const int s = sb + sl;
        const float px = grids[(g * 3 + 0) * S_ + s];
        const float py = grids[(g * 3 + 1) * S_ + s];
        const float pz = grids[(g * 3 + 2) * S_ + s];
        const float* Ev = Em + vL * 12;
        const float pi0 = Ev[0] * px + Ev[1] * py + Ev[2] * pz + Ev[3];
        const float pi1 = Ev[4] * px + Ev[5] * py + Ev[6] * pz + Ev[7];
        float z = Ev[8] * px + Ev[9] * py + Ev[10] * pz + Ev[11];
        if (fabsf(z) < VFS_EPS) z = 1.0f;
        const float xn = pi0 / z;
        const float yn = pi1 / z;
        const float r2 = xn * xn + yn * yn;
        const float fd = 1.0f + dst[vL * 2 + 0] * r2 + dst[vL * 2 + 1] * r2 * r2;
        const float xd = xn * fd, yd = yn * fd;
        const float* Kv = Km + vL * 9;
        const float pk0 = Kv[0] * xd + Kv[1] * yd + Kv[2];
        const float pk1 = Kv[3] * xd + Kv[4] * yd + Kv[5];
        const float u = 2.0f * pk0 / (W_ - 1.0f) - 1.0f;
        const float vq = 2.0f * pk1 / (H_ - 1.0f) - 1.0f;
        const bool inside = (u >= -1.0f) && (u <= 1.0f) && (vq >= -1.0f) && (vq <= 1.0f);
        const float x = (u + 1.0f) * (W_ * 0.5f) - 0.5f;
        const float y = (vq + 1.0f) * (H_ * 0.5f) - 0.5f;
        const float x0f = floorf(x), y0f = floorf(y);
        const float wx = x - x0f, wy = y - y0f;
        const int x0 = (int)x0f, y0 = (int)y0f;
        const float dx = px - cc[vL * 3 + 0];
        const float dy = py - cc[vL * 3 + 1];
        const float dz = pz - cc[vL * 3 + 2];
        float nrm = sqrtf(dx * dx + dy * dy + dz * dz);
        nrm = fmaxf(nrm, 1e-12f);
        float cosv = (dx * nx + dy * ny + dz * nz) / nrm;
        cosv = fminf(cosv, 0.0f);
        const float wraw = vis[vL * G_ + g] * (-cosv) * (inside ? 1.0f : 0.0f);
        const float bx = 50.0f * wraw;
        float w = (bx > 5.0f) ? wraw : (log1pf(expf(bx)) * (1.0f / 50.0f));
        float wsum = w;
        wsum += __shfl_xor(wsum, 1);
        wsum += __shfl_xor(wsum, 2);
        wsum += __shfl_xor(wsum, 4);
        w = w / wsum;
        wp[sl][vL] = make_float4(__int_as_float(x0), __int_as_float(y0), wx, wy);
        wv[sl][vL] = w;
    }
    __syncthreads();

    float mean[16], var[16];
#pragma unroll 2
    for (int j = 0; j < 16; ++j) {
        const int sl = wave * 16 + j;
        float m = 0.0f, m2 = 0.0f;
#pragma unroll
        for (int v = 0; v < 8; ++v) {
            const float4 q = wp[sl][v];
            const float w = wv[sl][v];
            const int x0 = __float_as_int(q.x);
            const int y0 = __float_as_int(q.y);
            const float wx = q.z, wy = q.w;
            const bool vx0 = (x0 >= 0) & (x0 < W_);
            const bool vx1 = (x0 >= -1) & (x0 < W_ - 1);
            const bool vy0 = (y0 >= 0) & (y0 < H_);
            const bool vy1 = (y0 >= -1) & (y0 < H_ - 1);
            const int xc0 = min(max(x0, 0), W_ - 1);
            const int xc1 = min(max(x0 + 1, 0), W_ - 1);
            const int yc0 = min(max(y0, 0), H_ - 1);
            const int yc1 = min(max(y0 + 1, 0), H_ - 1);
            const float* base = feat + (size_t)v * ((size_t)HW_ * F_) + (size_t)lane * HW_;
            const float g00 = base[(size_t)(yc0 * W_ + xc0)];
            const float g01 = base[(size_t)(yc0 * W_ + xc1)];
            const float g10 = base[(size_t)(yc1 * W_ + xc0)];
            const float g11 = base[(size_t)(yc1 * W_ + xc1)];
            const float f00 = (vx0 & vy0) ? (1.f - wx) * (1.f - wy) : 0.f;
            const float f01 = (vx1 & vy0) ? wx * (1.f - wy) : 0.f;
            const float f10 = (vx0 & vy1) ? (1.f - wx) * wy : 0.f;
            const float f11 = (vx1 & vy1) ? wx * wy : 0.f;
            const float fe = g00 * f00 + g01 * f01 + g10 * f10 + g11 * f11;
            m += w * fe;
            m2 += w * fe * fe;
        }
        mean[j] = m;
        var[j] = m2 - m * m;
    }

#pragma unroll
    for (int j = 0; j < 16; ++j) stg[wave * 16 + j][lane] = mean[j];
    __syncthreads();
#pragma unroll
    for (int i = 0; i < 16; ++i) {
        const int e = t + i * 256;
        const int f = e >> 6;
        const int sl = e & 63;
        out[((size_t)(g * 2 * F_ + f)) * S_ + sb + sl] = stg[sl][f];
    }
    __syncthreads();
#pragma unroll
    for (int j = 0; j < 16; ++j) stg[wave * 16 + j][lane] = var[j];
    __syncthreads();
#pragma unroll
    for (int i = 0; i < 16; ++i) {
        const int e = t + i * 256;
        const int f = e >> 6;
        const int sl = e & 63;
        out[((size_t)(g * 2 * F_ + F_ + f)) * S_ + sb + sl] = stg[sl][f];
    }
}

extern "C" void kernel_launch(void* const* d_in, const int* in_sizes, int n_in,
                              void* d_out, int out_size, void* d_ws, size_t ws_size,
                              hipStream_t stream) {
    const float* fm      = (const float*)d_in[0]; // [1][8][64][256][256]
    const float* Km      = (const float*)d_in[1]; // [1][8][3][3]
    const float* Em      = (const float*)d_in[2]; // [1][8][3][4]
    const float* dist    = (const float*)d_in[3]; // [1][8][2]
    const float* grids   = (const float*)d_in[4]; // [1][128][3][8][8][8]
    const float* vis     = (const float*)d_in[5]; // [1][8][128]
    const float* normals = (const float*)d_in[6]; // [1][128][3]
    const float* cc      = (const float*)d_in[7]; // [1][8][3]
    float* out           = (float*)d_out;         // [1][128][128][8][8][8]

    const size_t tsize = (size_t)V_ * F_ * HW_ * sizeof(__half); // 67 MB
    if (ws_size >= tsize) {
        vfs_transpose_h<<<dim3(HW_ / TPX, V_), 512, 0, stream>>>(fm, (__half*)d_ws);
        vfs_sampler_h2<<<G_ * 8, 256, 0, stream>>>((const __half*)d_ws, Km, Em, dist,
                                                   grids, vis, normals, cc, out);
    } else {
        vfs_sampler_f32<<<G_ * 8, 256, 0, stream>>>(fm, Km, Em, dist,
                                                    grids, vis, normals, cc, out);
    }
}

// Round 11
// 95.097 us; speedup vs baseline: 1.1446x; 1.1446x over previous
//
#include <hip/hip_runtime.h>
#include <hip/hip_fp16.h>
#include <math.h>

#define VFS_EPS 1e-7f

constexpr int V_ = 8, F_ = 64, H_ = 256, W_ = 256, G_ = 128, S_ = 512;
constexpr int HW_ = H_ * W_;
constexpr int TPX = 512;  // pixels per transpose tile

__device__ __forceinline__ __half2 vfs_uint_as_half2(uint u) {
    union { uint u; __half2 h; } c;
    c.u = u;
    return c.h;
}

__device__ __forceinline__ float vfs_h2sel(uint u, bool hi) {
    const __half2 h = vfs_uint_as_half2(u);
    return __half2float(hi ? __high2half(h) : __low2half(h));
}

// -------- K0: transpose+convert [V][F][HW] f32 -> [V][HW][F] f16 --------
// Validated R4-R10: ~27 us. Works because fm(134MB)+ws(67MB) co-reside in
// the 256MB L3 during replay; f32 ws (128MB) overflows L3 and lands at
// ~78 us regardless of structure (R1/R2/R3/R9 quad-confirmed).
__global__ __launch_bounds__(512) void vfs_transpose_h(const float* __restrict__ src,
                                                       __half* __restrict__ dst) {
    __shared__ ushort L[TPX][64];  // 64 KB
    const int v = blockIdx.y;
    const int p0 = blockIdx.x * TPX;
    const int t = threadIdx.x;
    const float* s = src + (size_t)v * F_ * HW_ + p0;
#pragma unroll 8
    for (int c = 0; c < F_; ++c) {
        const float val = s[(size_t)c * HW_ + t];
        const int os = (c >> 3) ^ (t & 7);
        L[t][os * 8 + (c & 7)] = __half_as_ushort(__float2half(val));
    }
    __syncthreads();
    __half* d = dst + ((size_t)v * HW_ + p0) * F_;
#pragma unroll
    for (int i = 0; i < 8; ++i) {
        const int j = i * 512 + t;
        const int p = j >> 3;
        const int o = j & 7;
        const int os = o ^ (p & 7);
        const uint4 val = *reinterpret_cast<const uint4*>(&L[p][os * 8]);
        *reinterpret_cast<uint4*>(&d[(size_t)j * 8]) = val;
    }
}

// -------- K1: R2-exact structure, f16 ws --------
// lane = channel; lanes 2k/2k+1 load the SAME uint (channels 2k,2k+1) ->
// one 128B line per corner per wave. Register accumulation mean[16]/var[16]
// across ALL points; LDS touched only in the final writeout (no per-point
// vmcnt drain -- the R2 property that made it 26us).
__global__ __launch_bounds__(256) void vfs_sampler_h2r(
    const __half* __restrict__ feat,
    const float* __restrict__ Km, const float* __restrict__ Em,
    const float* __restrict__ dst, const float* __restrict__ grids,
    const float* __restrict__ vis, const float* __restrict__ normals,
    const float* __restrict__ cc, float* __restrict__ out) {
    __shared__ float4 wp[64][8];   // {x0 bits, y0 bits, wx, wy} per (s_local, view)
    __shared__ float wv[64][8];    // normalized view weight
    __shared__ float stg[64][65];  // single staging buffer (R2-proven)

    const int g = blockIdx.x >> 3;
    const int sb = (blockIdx.x & 7) * 64;
    const int t = threadIdx.x;
    const int wave = t >> 6;
    const int lane = t & 63;
    const int vL = lane & 7;   // view (Phase A role)
    const int pL = lane >> 3;  // point-in-group (Phase A role)

    const float nx = normals[g * 3 + 0];
    const float ny = normals[g * 3 + 1];
    const float nz = normals[g * 3 + 2];

    // ---- Phase A: per (point, view) sampling params + normalized weights ----
#pragma unroll
    for (int grp = 0; grp < 2; ++grp) {
        const int sl = wave * 16 + grp * 8 + pL;
        const int s = sb + sl;
        const float px = grids[(g * 3 + 0) * S_ + s];
        const float py = grids[(g * 3 + 1) * S_ + s];
        const float pz = grids[(g * 3 + 2) * S_ + s];
        const float* Ev = Em + vL * 12;
        const float pi0 = Ev[0] * px + Ev[1] * py + Ev[2] * pz + Ev[3];
        const float pi1 = Ev[4] * px + Ev[5] * py + Ev[6] * pz + Ev[7];
        float z = Ev[8] * px + Ev[9] * py + Ev[10] * pz + Ev[11];
        if (fabsf(z) < VFS_EPS) z = 1.0f;
        const float xn = pi0 / z;
        const float yn = pi1 / z;
        const float r2 = xn * xn + yn * yn;
        const float fd = 1.0f + dst[vL * 2 + 0] * r2 + dst[vL * 2 + 1] * r2 * r2;
        const float xd = xn * fd, yd = yn * fd;
        const float* Kv = Km + vL * 9;
        const float pk0 = Kv[0] * xd + Kv[1] * yd + Kv[2];
        const float pk1 = Kv[3] * xd + Kv[4] * yd + Kv[5];
        const float u = 2.0f * pk0 / (W_ - 1.0f) - 1.0f;
        const float vq = 2.0f * pk1 / (H_ - 1.0f) - 1.0f;
        const bool inside = (u >= -1.0f) && (u <= 1.0f) && (vq >= -1.0f) && (vq <= 1.0f);
        const float x = (u + 1.0f) * (W_ * 0.5f) - 0.5f;
        const float y = (vq + 1.0f) * (H_ * 0.5f) - 0.5f;
        const float x0f = floorf(x), y0f = floorf(y);
        const float wx = x - x0f, wy = y - y0f;
        const int x0 = (int)x0f, y0 = (int)y0f;
        const float dx = px - cc[vL * 3 + 0];
        const float dy = py - cc[vL * 3 + 1];
        const float dz = pz - cc[vL * 3 + 2];
        float nrm = sqrtf(dx * dx + dy * dy + dz * dz);
        nrm = fmaxf(nrm, 1e-12f);
        float cosv = (dx * nx + dy * ny + dz * nz) / nrm;
        cosv = fminf(cosv, 0.0f);
        const float wraw = vis[vL * G_ + g] * (-cosv) * (inside ? 1.0f : 0.0f);
        const float bx = 50.0f * wraw;
        float w = (bx > 5.0f) ? wraw : (log1pf(expf(bx)) * (1.0f / 50.0f));
        float wsum = w;
        wsum += __shfl_xor(wsum, 1);
        wsum += __shfl_xor(wsum, 2);
        wsum += __shfl_xor(wsum, 4);
        w = w / wsum;
        wp[sl][vL] = make_float4(__int_as_float(x0), __int_as_float(y0), wx, wy);
        wv[sl][vL] = w;
    }
    __syncthreads();

    // ---- Phase B: lane = channel; branchless gather, register accumulation ----
    const uint* fp = reinterpret_cast<const uint*>(feat);
    const uint laneoff = (uint)(lane >> 1);   // word within pixel (loop-invariant)
    const bool hiHalf = (lane & 1) != 0;
    float mean[16], var[16];
#pragma unroll 2
    for (int j = 0; j < 16; ++j) {
        const int sl = wave * 16 + j;   // uniform across wave -> LDS broadcast
        float m = 0.0f, m2 = 0.0f;
#pragma unroll
        for (int v = 0; v < 8; ++v) {
            const float4 q = wp[sl][v];
            const float w = wv[sl][v];
            const int x0 = __float_as_int(q.x);
            const int y0 = __float_as_int(q.y);
            const float wx = q.z, wy = q.w;
            const bool vx0 = (x0 >= 0) & (x0 < W_);
            const bool vx1 = (x0 >= -1) & (x0 < W_ - 1);
            const bool vy0 = (y0 >= 0) & (y0 < H_);
            const bool vy1 = (y0 >= -1) & (y0 < H_ - 1);
            const int xc0 = min(max(x0, 0), W_ - 1);
            const int xc1 = min(max(x0 + 1, 0), W_ - 1);
            const int yc0 = min(max(y0, 0), H_ - 1);
            const int yc1 = min(max(y0 + 1, 0), H_ - 1);
            const uint b = ((uint)(v * HW_) << 5) + laneoff;
            const uint u00 = fp[b + ((uint)(yc0 * W_ + xc0) << 5)];
            const uint u01 = fp[b + ((uint)(yc0 * W_ + xc1) << 5)];
            const uint u10 = fp[b + ((uint)(yc1 * W_ + xc0) << 5)];
            const uint u11 = fp[b + ((uint)(yc1 * W_ + xc1) << 5)];
            const float g00 = vfs_h2sel(u00, hiHalf);
            const float g01 = vfs_h2sel(u01, hiHalf);
            const float g10 = vfs_h2sel(u10, hiHalf);
            const float g11 = vfs_h2sel(u11, hiHalf);
            const float f00 = (vx0 & vy0) ? (1.f - wx) * (1.f - wy) : 0.f;
            const float f01 = (vx1 & vy0) ? wx * (1.f - wy) : 0.f;
            const float f10 = (vx0 & vy1) ? (1.f - wx) * wy : 0.f;
            const float f11 = (vx1 & vy1) ? wx * wy : 0.f;
            const float fe = g00 * f00 + g01 * f01 + g10 * f10 + g11 * f11;
            m += w * fe;
            m2 += w * fe * fe;
        }
        mean[j] = m;
        var[j] = m2 - m * m;
    }

    // ---- coalesced write-out via single staging buffer, two passes ----
#pragma unroll
    for (int j = 0; j < 16; ++j) stg[wave * 16 + j][lane] = mean[j];
    __syncthreads();
#pragma unroll
    for (int i = 0; i < 16; ++i) {
        const int e = t + i * 256;
        const int f = e >> 6;
        const int sl = e & 63;
        out[((size_t)(g * 2 * F_ + f)) * S_ + sb + sl] = stg[sl][f];
    }
    __syncthreads();
#pragma unroll
    for (int j = 0; j < 16; ++j) stg[wave * 16 + j][lane] = var[j];
    __syncthreads();
#pragma unroll
    for (int i = 0; i < 16; ++i) {
        const int e = t + i * 256;
        const int f = e >> 6;
        const int sl = e & 63;
        out[((size_t)(g * 2 * F_ + F_ + f)) * S_ + sb + sl] = stg[sl][f];
    }
}

// -------- K1 fallback (raw f32 layout), from R2 (validated) --------
__global__ __launch_bounds__(256) void vfs_sampler_f32(
    const float* __restrict__ feat,
    const float* __restrict__ Km, const float* __restrict__ Em,
    const float* __restrict__ dst, const float* __restrict__ grids,
    const float* __restrict__ vis, const float* __restrict__ normals,
    const float* __restrict__ cc, float* __restrict__ out) {
    __shared__ float4 wp[64][8];
    __shared__ float wv[64][8];
    __shared__ float stg[64][65];

    const int g = blockIdx.x >> 3;
    const int sb = (blockIdx.x & 7) * 64;
    const int t = threadIdx.x;
    const int wave = t >> 6;
    const int lane = t & 63;
    const int vL = lane & 7;
    const int pL = lane >> 3;

    const float nx = normals[g * 3 + 0];
    const float ny = normals[g * 3 + 1];
    const float nz = normals[g * 3 + 2];

#pragma unroll
    for (int grp = 0; grp < 2; ++grp) {
        const int sl = wave * 16 + grp * 8 + pL;
        const int s = sb + sl;
        const float px = grids[(g * 3 + 0) * S_ + s];
        const float py = grids[(g * 3 + 1) * S_ + s];
        const float pz = grids[(g * 3 + 2) * S_ + s];
        const float* Ev = Em + vL * 12;
        const float pi0 = Ev[0] * px + Ev[1] * py + Ev[2] * pz + Ev[3];
        const float pi1 = Ev[4] * px + Ev[5] * py + Ev[6] * pz + Ev[7];
        float z = Ev[8] * px + Ev[9] * py + Ev[10] * pz + Ev[11];
        if (fabsf(z) < VFS_EPS) z = 1.0f;
        const float xn = pi0 / z;
        const float yn = pi1 / z;
        const float r2 = xn * xn + yn * yn;
        const float fd = 1.0f + dst[vL * 2 + 0] * r2 + dst[vL * 2 + 1] * r2 * r2;
        const float xd = xn * fd, yd = yn * fd;
        const float* Kv = Km + vL * 9;
        const float pk0 = Kv[0] * xd + Kv[1] * yd + Kv[2];
        const float pk1 = Kv[3] * xd + Kv[4] * yd + Kv[5];
        const float u = 2.0f * pk0 / (W_ - 1.0f) - 1.0f;
        const float vq = 2.0f * pk1 / (H_ - 1.0f) - 1.0f;
        const bool inside = (u >= -1.0f) && (u <= 1.0f) && (vq >= -1.0f) && (vq <= 1.0f);
        const float x = (u + 1.0f) * (W_ * 0.5f) - 0.5f;
        const float y = (vq + 1.0f) * (H_ * 0.5f) - 0.5f;
        const float x0f = floorf(x), y0f = floorf(y);
        const float wx = x - x0f, wy = y - y0f;
        const int x0 = (int)x0f, y0 = (int)y0f;
        const float dx = px - cc[vL * 3 + 0];
        const float dy = py - cc[vL * 3 + 1];
        const float dz = pz - cc[vL * 3 + 2];
        float nrm = sqrtf(dx * dx + dy * dy + dz * dz);
        nrm = fmaxf(nrm, 1e-12f);
        float cosv = (dx * nx + dy * ny + dz * nz) / nrm;
        cosv = fminf(cosv, 0.0f);
        const float wraw = vis[vL * G_ + g] * (-cosv) * (inside ? 1.0f : 0.0f);
        const float bx = 50.0f * wraw;
        float w = (bx > 5.0f) ? wraw : (log1pf(expf(bx)) * (1.0f / 50.0f));
        float wsum = w;
        wsum += __shfl_xor(wsum, 1);
        wsum += __shfl_xor(wsum, 2);
        wsum += __shfl_xor(wsum, 4);
        w = w / wsum;
        wp[sl][vL] = make_float4(__int_as_float(x0), __int_as_float(y0), wx, wy);
        wv[sl][vL] = w;
    }
    __syncthreads();

    float mean[16], var[16];
#pragma unroll 2
    for (int j = 0; j < 16; ++j) {
        const int sl = wave * 16 + j;
        float m = 0.0f, m2 = 0.0f;
#pragma unroll
        for (int v = 0; v < 8; ++v) {
            const float4 q = wp[sl][v];
            const float w = wv[sl][v];
            const int x0 = __float_as_int(q.x);
            const int y0 = __float_as_int(q.y);
            const float wx = q.z, wy = q.w;
            const bool vx0 = (x0 >= 0) & (x0 < W_);
            const bool vx1 = (x0 >= -1) & (x0 < W_ - 1);
            const bool vy0 = (y0 >= 0) & (y0 < H_);
            const bool vy1 = (y0 >= -1) & (y0 < H_ - 1);
            const int xc0 = min(max(x0, 0), W_ - 1);
            const int xc1 = min(max(x0 + 1, 0), W_ - 1);
            const int yc0 = min(max(y0, 0), H_ - 1);
            const int yc1 = min(max(y0 + 1, 0), H_ - 1);
            const float* base = feat + (size_t)v * ((size_t)HW_ * F_) + (size_t)lane * HW_;
            const float g00 = base[(size_t)(yc0 * W_ + xc0)];
            const float g01 = base[(size_t)(yc0 * W_ + xc1)];
            const float g10 = base[(size_t)(yc1 * W_ + xc0)];
            const float g11 = base[(size_t)(yc1 * W_ + xc1)];
            const float f00 = (vx0 & vy0) ? (1.f - wx) * (1.f - wy) : 0.f;
            const float f01 = (vx1 & vy0) ? wx * (1.f - wy) : 0.f;
            const float f10 = (vx0 & vy1) ? (1.f - wx) * wy : 0.f;
            const float f11 = (vx1 & vy1) ? wx * wy : 0.f;
            const float fe = g00 * f00 + g01 * f01 + g10 * f10 + g11 * f11;
            m += w * fe;
            m2 += w * fe * fe;
        }
        mean[j] = m;
        var[j] = m2 - m * m;
    }

#pragma unroll
    for (int j = 0; j < 16; ++j) stg[wave * 16 + j][lane] = mean[j];
    __syncthreads();
#pragma unroll
    for (int i = 0; i < 16; ++i) {
        const int e = t + i * 256;
        const int f = e >> 6;
        const int sl = e & 63;
        out[((size_t)(g * 2 * F_ + f)) * S_ + sb + sl] = stg[sl][f];
    }
    __syncthreads();
#pragma unroll
    for (int j = 0; j < 16; ++j) stg[wave * 16 + j][lane] = var[j];
    __syncthreads();
#pragma unroll
    for (int i = 0; i < 16; ++i) {
        const int e = t + i * 256;
        const int f = e >> 6;
        const int sl = e & 63;
        out[((size_t)(g * 2 * F_ + F_ + f)) * S_ + sb + sl] = stg[sl][f];
    }
}

extern "C" void kernel_launch(void* const* d_in, const int* in_sizes, int n_in,
                              void* d_out, int out_size, void* d_ws, size_t ws_size,
                              hipStream_t stream) {
    const float* fm      = (const float*)d_in[0]; // [1][8][64][256][256]
    const float* Km      = (const float*)d_in[1]; // [1][8][3][3]
    const float* Em      = (const float*)d_in[2]; // [1][8][3][4]
    const float* dist    = (const float*)d_in[3]; // [1][8][2]
    const float* grids   = (const float*)d_in[4]; // [1][128][3][8][8][8]
    const float* vis     = (const float*)d_in[5]; // [1][8][128]
    const float* normals = (const float*)d_in[6]; // [1][128][3]
    const float* cc      = (const float*)d_in[7]; // [1][8][3]
    float* out           = (float*)d_out;         // [1][128][128][8][8][8]

    const size_t tsize = (size_t)V_ * F_ * HW_ * sizeof(__half); // 67 MB
    if (ws_size >= tsize) {
        vfs_transpose_h<<<dim3(HW_ / TPX, V_), 512, 0, stream>>>(fm, (__half*)d_ws);
        vfs_sampler_h2r<<<G_ * 8, 256, 0, stream>>>((const __half*)d_ws, Km, Em, dist,
                                                    grids, vis, normals, cc, out);
    } else {
        vfs_sampler_f32<<<G_ * 8, 256, 0, stream>>>(fm, Km, Em, dist,
                                                    grids, vis, normals, cc, out);
    }
}

// Round 12
// 78.899 us; speedup vs baseline: 1.3796x; 1.2053x over previous
//
#include <hip/hip_runtime.h>
#include <hip/hip_fp16.h>
#include <math.h>

#define VFS_EPS 1e-7f

constexpr int V_ = 8, F_ = 64, H_ = 256, W_ = 256, G_ = 128, S_ = 512;
constexpr int HW_ = H_ * W_;
constexpr int TPX = 512;  // pixels per transpose tile

__device__ __forceinline__ __half2 vfs_uint_as_half2(uint u) {
    union { uint u; __half2 h; } c;
    c.u = u;
    return c.h;
}

// -------- K0: transpose+convert [V][F][HW] f32 -> [V][HW][F] f16 --------
// Validated R4-R11: ~27 us (footprint fits L3; f32 variants thrash at ~78).
__global__ __launch_bounds__(512) void vfs_transpose_h(const float* __restrict__ src,
                                                       __half* __restrict__ dst) {
    __shared__ ushort L[TPX][64];  // 64 KB
    const int v = blockIdx.y;
    const int p0 = blockIdx.x * TPX;
    const int t = threadIdx.x;
    const float* s = src + (size_t)v * F_ * HW_ + p0;
#pragma unroll 8
    for (int c = 0; c < F_; ++c) {
        const float val = s[(size_t)c * HW_ + t];
        const int os = (c >> 3) ^ (t & 7);
        L[t][os * 8 + (c & 7)] = __half_as_ushort(__float2half(val));
    }
    __syncthreads();
    __half* d = dst + ((size_t)v * HW_ + p0) * F_;
#pragma unroll
    for (int i = 0; i < 8; ++i) {
        const int j = i * 512 + t;
        const int p = j >> 3;
        const int o = j & 7;
        const int os = o ^ (p & 7);
        const uint4 val = *reinterpret_cast<const uint4*>(&L[p][os * 8]);
        *reinterpret_cast<uint4*>(&d[(size_t)j * 8]) = val;
    }
}

// -------- K1 (f16 ws): R5-exact loop, packed side tables -> 4 blocks/CU ----
// R5 champion (50us) had 43.5KB LDS = 3 blocks/CU; grid 1024 > 768 resident
// => 25% scheduling tail. Packing wp(16B)->wq(8B: xy0 9+9 bits, wx/wy f16x2)
// cuts LDS to 39.4KB = 4 blocks/CU = 1024 resident, no tail. Loop body,
// lane mapping, staging identical to R5.
__global__ __launch_bounds__(256, 4) void vfs_sampler_h2(
    const __half* __restrict__ feat,
    const float* __restrict__ Km, const float* __restrict__ Em,
    const float* __restrict__ dst, const float* __restrict__ grids,
    const float* __restrict__ vis, const float* __restrict__ normals,
    const float* __restrict__ cc, float* __restrict__ out) {
    __shared__ uint2 wq[64][8];    // packed {x0,y0 | wx,wy}        (4 KB)
    __shared__ float wv[64][8];    // normalized view weight        (2 KB)
    __shared__ float stgM[64][65]; // mean staging                  (16.6 KB)
    __shared__ float stgV[64][65]; // var staging                   (16.6 KB)

    const int g = blockIdx.x >> 3;
    const int sb = (blockIdx.x & 7) * 64;
    const int t = threadIdx.x;
    const int wave = t >> 6;
    const int lane = t & 63;

    // ---- Phase A: lane = (point8, view8); params + normalized weights ----
    {
        const int vL = lane & 7;
        const int pL = lane >> 3;
        const float nx = normals[g * 3 + 0];
        const float ny = normals[g * 3 + 1];
        const float nz = normals[g * 3 + 2];
#pragma unroll
        for (int grp = 0; grp < 2; ++grp) {
            const int sl = wave * 16 + grp * 8 + pL;
            const int s = sb + sl;
            const float px = grids[(g * 3 + 0) * S_ + s];
            const float py = grids[(g * 3 + 1) * S_ + s];
            const float pz = grids[(g * 3 + 2) * S_ + s];
            const float* Ev = Em + vL * 12;
            const float pi0 = Ev[0] * px + Ev[1] * py + Ev[2] * pz + Ev[3];
            const float pi1 = Ev[4] * px + Ev[5] * py + Ev[6] * pz + Ev[7];
            float z = Ev[8] * px + Ev[9] * py + Ev[10] * pz + Ev[11];
            if (fabsf(z) < VFS_EPS) z = 1.0f;
            const float xn = pi0 / z;
            const float yn = pi1 / z;
            const float r2 = xn * xn + yn * yn;
            const float fd = 1.0f + dst[vL * 2 + 0] * r2 + dst[vL * 2 + 1] * r2 * r2;
            const float xd = xn * fd, yd = yn * fd;
            const float* Kv = Km + vL * 9;
            const float pk0 = Kv[0] * xd + Kv[1] * yd + Kv[2];
            const float pk1 = Kv[3] * xd + Kv[4] * yd + Kv[5];
            const float u = 2.0f * pk0 / (W_ - 1.0f) - 1.0f;
            const float vq = 2.0f * pk1 / (H_ - 1.0f) - 1.0f;
            const bool inside = (u >= -1.0f) && (u <= 1.0f) && (vq >= -1.0f) && (vq <= 1.0f);
            const float x = (u + 1.0f) * (W_ * 0.5f) - 0.5f;
            const float y = (vq + 1.0f) * (H_ * 0.5f) - 0.5f;
            const float x0f = floorf(x), y0f = floorf(y);
            const float wx = x - x0f, wy = y - y0f;
            const int x0 = (int)x0f, y0 = (int)y0f;
            const float dx = px - cc[vL * 3 + 0];
            const float dy = py - cc[vL * 3 + 1];
            const float dz = pz - cc[vL * 3 + 2];
            float nrm = sqrtf(dx * dx + dy * dy + dz * dz);
            nrm = fmaxf(nrm, 1e-12f);
            float cosv = (dx * nx + dy * ny + dz * nz) / nrm;
            cosv = fminf(cosv, 0.0f);
            const float wraw = vis[vL * G_ + g] * (-cosv) * (inside ? 1.0f : 0.0f);
            const float bx = 50.0f * wraw;
            float w = (bx > 5.0f) ? wraw : (log1pf(expf(bx)) * (1.0f / 50.0f));
            float wsum = w;
            wsum += __shfl_xor(wsum, 1);
            wsum += __shfl_xor(wsum, 2);
            wsum += __shfl_xor(wsum, 4);
            w = w / wsum;
            // pack: clamp (x0,y0) to [-2, W]/[-2, H] (validity-equivalent),
            // 9+9 bits; (wx,wy) as f16 pair (error <= ~1e-3, budget 0.088).
            const uint xcp = (uint)(min(max(x0, -2), W_) + 2);
            const uint ycp = (uint)(min(max(y0, -2), H_) + 2);
            const uint wxy = (uint)__half_as_ushort(__float2half(wx)) |
                             ((uint)__half_as_ushort(__float2half(wy)) << 16);
            wq[sl][vL] = make_uint2(xcp | (ycp << 9), wxy);
            wv[sl][vL] = w;
        }
    }
    __syncthreads();

    // ---- Phase B (R5-exact): wave = 2 points x 32 ch-pairs, half2 gathers ----
    const int sub = lane >> 5;  // which point of the pair
    const int cp = lane & 31;   // channel pair -> channels 2cp, 2cp+1
    const uint* fp = reinterpret_cast<const uint*>(feat);
    for (int jj = 0; jj < 8; ++jj) {
        const int sl = wave * 16 + jj * 2 + sub;
        float mx = 0.f, my = 0.f, qx = 0.f, qy = 0.f;
#pragma unroll
        for (int v = 0; v < 8; ++v) {
            const uint2 q = wq[sl][v];   // broadcast within half-wave
            const float w = wv[sl][v];
            const int x0 = (int)(q.x & 511u) - 2;
            const int y0 = (int)((q.x >> 9) & 511u) - 2;
            const float2 wxy = __half22float2(vfs_uint_as_half2(q.y));
            const float wx = wxy.x, wy = wxy.y;
            const bool vx0 = (x0 >= 0) & (x0 < W_);
            const bool vx1 = (x0 >= -1) & (x0 < W_ - 1);
            const bool vy0 = (y0 >= 0) & (y0 < H_);
            const bool vy1 = (y0 >= -1) & (y0 < H_ - 1);
            const int xc0 = min(max(x0, 0), W_ - 1);
            const int xc1 = min(max(x0 + 1, 0), W_ - 1);
            const int yc0 = min(max(y0, 0), H_ - 1);
            const int yc1 = min(max(y0 + 1, 0), H_ - 1);
            const uint base = (uint)(v * HW_) * 32u + (uint)cp;
            const uint i00 = base + (uint)(yc0 * W_ + xc0) * 32u;
            const uint i01 = base + (uint)(yc0 * W_ + xc1) * 32u;
            const uint i10 = base + (uint)(yc1 * W_ + xc0) * 32u;
            const uint i11 = base + (uint)(yc1 * W_ + xc1) * 32u;
            const float2 g00 = __half22float2(*reinterpret_cast<const __half2*>(fp + i00));
            const float2 g01 = __half22float2(*reinterpret_cast<const __half2*>(fp + i01));
            const float2 g10 = __half22float2(*reinterpret_cast<const __half2*>(fp + i10));
            const float2 g11 = __half22float2(*reinterpret_cast<const __half2*>(fp + i11));
            const float f00 = (vx0 & vy0) ? (1.f - wx) * (1.f - wy) : 0.f;
            const float f01 = (vx1 & vy0) ? wx * (1.f - wy) : 0.f;
            const float f10 = (vx0 & vy1) ? (1.f - wx) * wy : 0.f;
            const float f11 = (vx1 & vy1) ? wx * wy : 0.f;
            const float fex = g00.x * f00 + g01.x * f01 + g10.x * f10 + g11.x * f11;
            const float fey = g00.y * f00 + g01.y * f01 + g10.y * f10 + g11.y * f11;
            mx += w * fex;
            qx += w * fex * fex;
            my += w * fey;
            qy += w * fey * fey;
        }
        stgM[sl][2 * cp + 0] = mx;
        stgM[sl][2 * cp + 1] = my;
        stgV[sl][2 * cp + 0] = qx - mx * mx;
        stgV[sl][2 * cp + 1] = qy - my * my;
    }
    __syncthreads();

    // ---- coalesced write-out (R5-exact) ----
#pragma unroll
    for (int i = 0; i < 16; ++i) {
        const int e = t + i * 256;
        const int f = e >> 6;
        const int sl = e & 63;
        out[((size_t)(g * 2 * F_ + f)) * S_ + sb + sl] = stgM[sl][f];
    }
#pragma unroll
    for (int i = 0; i < 16; ++i) {
        const int e = t + i * 256;
        const int f = e >> 6;
        const int sl = e & 63;
        out[((size_t)(g * 2 * F_ + F_ + f)) * S_ + sb + sl] = stgV[sl][f];
    }
}

// -------- K1 fallback (raw f32 layout), from R2 (validated) --------
__global__ __launch_bounds__(256) void vfs_sampler_f32(
    const float* __restrict__ feat,
    const float* __restrict__ Km, const float* __restrict__ Em,
    const float* __restrict__ dst, const float* __restrict__ grids,
    const float* __restrict__ vis, const float* __restrict__ normals,
    const float* __restrict__ cc, float* __restrict__ out) {
    __shared__ float4 wp[64][8];
    __shared__ float wv[64][8];
    __shared__ float stg[64][65];

    const int g = blockIdx.x >> 3;
    const int sb = (blockIdx.x & 7) * 64;
    const int t = threadIdx.x;
    const int wave = t >> 6;
    const int lane = t & 63;
    const int vL = lane & 7;
    const int pL = lane >> 3;

    const float nx = normals[g * 3 + 0];
    const float ny = normals[g * 3 + 1];
    const float nz = normals[g * 3 + 2];

#pragma unroll
    for (int grp = 0; grp < 2; ++grp) {
        const int sl = wave * 16 + grp * 8 + pL;
        const int s = sb + sl;
        const float px = grids[(g * 3 + 0) * S_ + s];
        const float py = grids[(g * 3 + 1) * S_ + s];
        const float pz = grids[(g * 3 + 2) * S_ + s];
        const float* Ev = Em + vL * 12;
        const float pi0 = Ev[0] * px + Ev[1] * py + Ev[2] * pz + Ev[3];
        const float pi1 = Ev[4] * px + Ev[5] * py + Ev[6] * pz + Ev[7];
        float z = Ev[8] * px + Ev[9] * py + Ev[10] * pz + Ev[11];
        if (fabsf(z) < VFS_EPS) z = 1.0f;
        const float xn = pi0 / z;
        const float yn = pi1 / z;
        const float r2 = xn * xn + yn * yn;
        const float fd = 1.0f + dst[vL * 2 + 0] * r2 + dst[vL * 2 + 1] * r2 * r2;
        const float xd = xn * fd, yd = yn * fd;
        const float* Kv = Km + vL * 9;
        const float pk0 = Kv[0] * xd + Kv[1] * yd + Kv[2];
        const float pk1 = Kv[3] * xd + Kv[4] * yd + Kv[5];
        const float u = 2.0f * pk0 / (W_ - 1.0f) - 1.0f;
        const float vq = 2.0f * pk1 / (H_ - 1.0f) - 1.0f;
        const bool inside = (u >= -1.0f) && (u <= 1.0f) && (vq >= -1.0f) && (vq <= 1.0f);
        const float x = (u + 1.0f) * (W_ * 0.5f) - 0.5f;
        const float y = (vq + 1.0f) * (H_ * 0.5f) - 0.5f;
        const float x0f = floorf(x), y0f = floorf(y);
        const float wx = x - x0f, wy = y - y0f;
        const int x0 = (int)x0f, y0 = (int)y0f;
        const float dx = px - cc[vL * 3 + 0];
        const float dy = py - cc[vL * 3 + 1];
        const float dz = pz - cc[vL * 3 + 2];
        float nrm = sqrtf(dx * dx + dy * dy + dz * dz);
        nrm = fmaxf(nrm, 1e-12f);
        float cosv = (dx * nx + dy * ny + dz * nz) / nrm;
        cosv = fminf(cosv, 0.0f);
        const float wraw = vis[vL * G_ + g] * (-cosv) * (inside ? 1.0f : 0.0f);
        const float bx = 50.0f * wraw;
        float w = (bx > 5.0f) ? wraw : (log1pf(expf(bx)) * (1.0f / 50.0f));
        float wsum = w;
        wsum += __shfl_xor(wsum, 1);
        wsum += __shfl_xor(wsum, 2);
        wsum += __shfl_xor(wsum, 4);
        w = w / wsum;
        wp[sl][vL] = make_float4(__int_as_float(x0), __int_as_float(y0), wx, wy);
        wv[sl][vL] = w;
    }
    __syncthreads();

    float mean[16], var[16];
#pragma unroll 2
    for (int j = 0; j < 16; ++j) {
        const int sl = wave * 16 + j;
        float m = 0.0f, m2 = 0.0f;
#pragma unroll
        for (int v = 0; v < 8; ++v) {
            const float4 q = wp[sl][v];
            const float w = wv[sl][v];
            const int x0 = __float_as_int(q.x);
            const int y0 = __float_as_int(q.y);
            const float wx = q.z, wy = q.w;
            const bool vx0 = (x0 >= 0) & (x0 < W_);
            const bool vx1 = (x0 >= -1) & (x0 < W_ - 1);
            const bool vy0 = (y0 >= 0) & (y0 < H_);
            const bool vy1 = (y0 >= -1) & (y0 < H_ - 1);
            const int xc0 = min(max(x0, 0), W_ - 1);
            const int xc1 = min(max(x0 + 1, 0), W_ - 1);
            const int yc0 = min(max(y0, 0), H_ - 1);
            const int yc1 = min(max(y0 + 1, 0), H_ - 1);
            const float* base = feat + (size_t)v * ((size_t)HW_ * F_) + (size_t)lane * HW_;
            const float g00 = base[(size_t)(yc0 * W_ + xc0)];
            const float g01 = base[(size_t)(yc0 * W_ + xc1)];
            const float g10 = base[(size_t)(yc1 * W_ + xc0)];
            const float g11 = base[(size_t)(yc1 * W_ + xc1)];
            const float f00 = (vx0 & vy0) ? (1.f - wx) * (1.f - wy) : 0.f;
            const float f01 = (vx1 & vy0) ? wx * (1.f - wy) : 0.f;
            const float f10 = (vx0 & vy1) ? (1.f - wx) * wy : 0.f;
            const float f11 = (vx1 & vy1) ? wx * wy : 0.f;
            const float fe = g00 * f00 + g01 * f01 + g10 * f10 + g11 * f11;
            m += w * fe;
            m2 += w * fe * fe;
        }
        mean[j] = m;
        var[j] = m2 - m * m;
    }

#pragma unroll
    for (int j = 0; j < 16; ++j) stg[wave * 16 + j][lane] = mean[j];
    __syncthreads();
#pragma unroll
    for (int i = 0; i < 16; ++i) {
        const int e = t + i * 256;
        const int f = e >> 6;
        const int sl = e & 63;
        out[((size_t)(g * 2 * F_ + f)) * S_ + sb + sl] = stg[sl][f];
    }
    __syncthreads();
#pragma unroll
    for (int j = 0; j < 16; ++j) stg[wave * 16 + j][lane] = var[j];
    __syncthreads();
#pragma unroll
    for (int i = 0; i < 16; ++i) {
        const int e = t + i * 256;
        const int f = e >> 6;
        const int sl = e & 63;
        out[((size_t)(g * 2 * F_ + F_ + f)) * S_ + sb + sl] = stg[sl][f];
    }
}

extern "C" void kernel_launch(void* const* d_in, const int* in_sizes, int n_in,
                              void* d_out, int out_size, void* d_ws, size_t ws_size,
                              hipStream_t stream) {
    const float* fm      = (const float*)d_in[0]; // [1][8][64][256][256]
    const float* Km      = (const float*)d_in[1]; // [1][8][3][3]
    const float* Em      = (const float*)d_in[2]; // [1][8][3][4]
    const float* dist    = (const float*)d_in[3]; // [1][8][2]
    const float* grids   = (const float*)d_in[4]; // [1][128][3][8][8][8]
    const float* vis     = (const float*)d_in[5]; // [1][8][128]
    const float* normals = (const float*)d_in[6]; // [1][128][3]
    const float* cc      = (const float*)d_in[7]; // [1][8][3]
    float* out           = (float*)d_out;         // [1][128][128][8][8][8]

    const size_t tsize = (size_t)V_ * F_ * HW_ * sizeof(__half); // 67 MB
    if (ws_size >= tsize) {
        vfs_transpose_h<<<dim3(HW_ / TPX, V_), 512, 0, stream>>>(fm, (__half*)d_ws);
        vfs_sampler_h2<<<G_ * 8, 256, 0, stream>>>((const __half*)d_ws, Km, Em, dist,
                                                   grids, vis, normals, cc, out);
    } else {
        vfs_sampler_f32<<<G_ * 8, 256, 0, stream>>>(fm, Km, Em, dist,
                                                    grids, vis, normals, cc, out);
    }
}